// Round 8
// baseline (196.715 us; speedup 1.0000x reference)
//
#include <hip/hip_runtime.h>

#define C_IN 256
#define CR   64      // C / reduction
#define G_   16
#define GC_  16
#define K_   7
#define KK   49
#define PAD_ 3
#define H_   64
#define W_   64
#define HW   4096
#define OO   784     // K^2 * G
#define EPSV 1e-5f
#define NT   13      // taps per wave in phase B (16*13=208 >= 196, clamped)
#define CHUNK_T 196  // taps per g-chunk (4 groups * 49)

// ---------------- prep: BN-folded transpose of w1, fold b1 ----------------
__global__ __launch_bounds__(256) void prep_kernel(
    const float* __restrict__ w1, const float* __restrict__ b1,
    const float* __restrict__ gamma, const float* __restrict__ beta,
    const float* __restrict__ mean, const float* __restrict__ var,
    float* __restrict__ w1t, float* __restrict__ b1f)
{
  int idx = blockIdx.x * 256 + threadIdx.x;
  if (idx < CR * C_IN) {                 // dst w1t[c][o]
    int c = idx / CR, o = idx % CR;
    float s = gamma[o] * rsqrtf(var[o] + EPSV);
    w1t[idx] = w1[o * C_IN + c] * s;
  }
  if (idx < CR) {
    float s = gamma[idx] * rsqrtf(var[idx] + EPSV);
    b1f[idx] = (b1[idx] - mean[idx]) * s + beta[idx];
  }
}

// ---------------- fully fused conv1+BN+ReLU -> conv2 -> involution --------
// block = one (b,row), 1024 threads = 16 waves. t and the 784x64 weight map
// live entirely in LDS. LDS: xs[256][64] 64KB (phase A, aliased by wl),
// tl[64][64] 16KB, wl[196][64] 50.2KB. Peak 80KB -> 1 block/CU, 4 waves/SIMD.
__global__ __launch_bounds__(1024) void fused_kernel(
    const float* __restrict__ x, const float* __restrict__ w1t,  // [c][o] 256x64
    const float* __restrict__ b1f,
    const float* __restrict__ w2,   // raw [oo=784][c=64]
    const float* __restrict__ b2, float* __restrict__ out)
{
  __shared__ float smem[20480];          // 80 KB
  float* xs = smem;                      // [256][64]  (phase A only)
  float* wl = smem;                      // [196][64]  (B/C, aliases xs)
  float* tl = smem + 16384;              // [64][64]
  const int tid = threadIdx.x;

  // XCD-sliced decode: XCD k (= blockIdx%8) gets a contiguous (b,row) slice
  // so the 7-row x halo stays in one XCD's L2.
  const int L   = blockIdx.x;
  const int per = gridDim.x >> 3;
  const int pr  = (L >> 3) + (L & 7) * per;
  const int b   = pr >> 6, row = pr & 63;

  // ---- cooperative x-row stage: 256 c x 64 px, each element once ----
  {
    const float* xrow = x + ((size_t)b * C_IN) * HW + row * W_;
    const int px4 = (tid & 15) * 4;
    const int c0  = tid >> 4;
#pragma unroll
    for (int r = 0; r < 4; ++r) {
      int c = c0 + r * 64;
      *(float4*)(xs + c * 64 + px4) =
          *(const float4*)(xrow + (size_t)c * HW + px4);
    }
  }
  __syncthreads();

  // ---- phase A: conv1 + BN + ReLU -> tl[o][px] ----
  {
    const int px = tid & 63;
    const int j  = __builtin_amdgcn_readfirstlane(tid >> 6);  // 0..15
    const int o0 = j * 4;
    float4 bb = *(const float4*)(b1f + o0);
    float acc[4] = {bb.x, bb.y, bb.z, bb.w};
#pragma unroll 8
    for (int c = 0; c < C_IN; ++c) {
      float xv  = xs[c * 64 + px];                       // ds_read, 2-way free
      float4 wv = *(const float4*)(w1t + c * CR + o0);   // uniform s_load_x4
      acc[0] = fmaf(xv, wv.x, acc[0]);
      acc[1] = fmaf(xv, wv.y, acc[1]);
      acc[2] = fmaf(xv, wv.z, acc[2]);
      acc[3] = fmaf(xv, wv.w, acc[3]);
    }
#pragma unroll
    for (int q = 0; q < 4; ++q)
      tl[(o0 + q) * 64 + px] = fmaxf(acc[q], 0.f);
  }
  __syncthreads();   // also fences xs reads before wl writes below

  // ---- 4 chunks of 4 groups: {B: gen weights} {C: apply} ----
#pragma unroll 1
  for (int gchunk = 0; gchunk < 4; ++gchunk) {
    const int oo0 = gchunk * CHUNK_T;      // global tap base (= oo index base)

    // phase B: conv2 for taps T in [0,196) of this chunk -> wl[T][px]
    {
      const int px = tid & 63;
      const int j  = __builtin_amdgcn_readfirstlane(tid >> 6);
      const int t0 = j * NT;
      float acc[NT];
#pragma unroll
      for (int i = 0; i < NT; ++i) {
        int T = t0 + i; T = T < CHUNK_T ? T : CHUNK_T - 1;   // clamp (benign dup)
        acc[i] = b2[oo0 + T];
      }
#pragma unroll 2
      for (int c0 = 0; c0 < CR; c0 += 8) {
        float tr[8];
#pragma unroll
        for (int q = 0; q < 8; ++q) tr[q] = tl[(c0 + q) * 64 + px];
#pragma unroll
        for (int i = 0; i < NT; ++i) {
          int T = t0 + i; T = T < CHUNK_T ? T : CHUNK_T - 1;
          const float* wr = w2 + (size_t)(oo0 + T) * CR + c0;  // uniform s_load_x8
#pragma unroll
          for (int q = 0; q < 8; ++q)
            acc[i] = fmaf(tr[q], wr[q], acc[i]);
        }
      }
#pragma unroll
      for (int i = 0; i < NT; ++i) {
        int T = t0 + i;
        if (T < CHUNK_T) wl[T * 64 + px] = acc[i];
      }
    }
    __syncthreads();

    // phase C: apply 4 groups; thread = (px-quad, gc, group-local gl)
    {
      const int quad = tid & 15;
      const int gc   = (tid >> 4) & 15;
      const int gl   = __builtin_amdgcn_readfirstlane(tid >> 8);  // 0..3
      const int ch   = (gchunk * 4 + gl) * GC_ + gc;
      const int w0   = quad * 4;

      float acc4[4] = {0.f, 0.f, 0.f, 0.f};
      const float* xp = x + ((size_t)b * C_IN + ch) * HW;
#pragma unroll
      for (int kh = 0; kh < K_; ++kh) {
        const int y = row + kh - PAD_;
        if ((unsigned)y < (unsigned)H_) {      // wave-uniform branch
          const float* xr = xp + y * W_;
          float win[12];
          float4 z4 = {0.f, 0.f, 0.f, 0.f};
          *(float4*)&win[0] = (w0 >= 4)  ? *(const float4*)(xr + w0 - 4) : z4;
          *(float4*)&win[4] = *(const float4*)(xr + w0);
          *(float4*)&win[8] = (w0 <= 56) ? *(const float4*)(xr + w0 + 4) : z4;
#pragma unroll
          for (int dw = 0; dw < K_; ++dw) {
            float wv[4];
            *(float4*)wv = *(const float4*)(wl + (gl * KK + kh * 7 + dw) * 64 + w0);
#pragma unroll
            for (int cc = 0; cc < 4; ++cc)
              acc4[cc] = fmaf(wv[cc], win[cc + dw + 1], acc4[cc]);
          }
        }
      }
      *(float4*)(out + ((size_t)b * C_IN + ch) * HW + row * W_ + w0) =
          *(float4*)acc4;
    }
    __syncthreads();   // wl reuse fence for next chunk
  }
}

extern "C" void kernel_launch(void* const* d_in, const int* in_sizes, int n_in,
                              void* d_out, int out_size, void* d_ws, size_t ws_size,
                              hipStream_t stream) {
  const float* x     = (const float*)d_in[0];
  const float* w1    = (const float*)d_in[1];
  const float* b1    = (const float*)d_in[2];
  const float* gamma = (const float*)d_in[3];
  const float* beta  = (const float*)d_in[4];
  const float* mean  = (const float*)d_in[5];
  const float* var   = (const float*)d_in[6];
  const float* w2    = (const float*)d_in[7];
  const float* b2    = (const float*)d_in[8];
  float* out = (float*)d_out;
  const int B = in_sizes[0] / (C_IN * HW);

  // ws: [w1t 64KB][b1f 256B]
  char* p = (char*)d_ws;
  float* w1t = (float*)p;  p += ((size_t)CR * C_IN * 4 + 255) & ~(size_t)255;
  float* b1f = (float*)p;

  prep_kernel<<<dim3((CR * C_IN + 255) / 256), 256, 0, stream>>>(
      w1, b1, gamma, beta, mean, var, w1t, b1f);

  fused_kernel<<<dim3(B * H_), 1024, 0, stream>>>(x, w1t, b1f, w2, b2, out);
}